// Round 3
// baseline (479.775 us; speedup 1.0000x reference)
//
#include <hip/hip_runtime.h>
#include <hip/hip_bf16.h>
#include <math.h>

#define N_NODES 50000
#define N_EDGES 800000

// ---------------------------------------------------------------------------
// GEMM: out[n][j] = sum_k act(in[n][k]) * W[k][j]
//   act(v) = ACT ? max(v + bias[k], 0) : v
// ---------------------------------------------------------------------------
template <int K, bool ACT>
__global__ __launch_bounds__(256) void gemm_act(
    const float* __restrict__ in, const float* __restrict__ W,
    const float* __restrict__ bias, float* __restrict__ out, int N)
{
    __shared__ float Wl[K * 64];
    __shared__ float xs[32][K];

    const int tid = threadIdx.x;
    const int j   = tid & 63;
    const int rq  = tid >> 6;            // 0..3
    const int base = blockIdx.x * 32;

    for (int i = tid; i < K * 64; i += 256) Wl[i] = W[i];

    for (int i = tid; i < 32 * K; i += 256) {
        const int r = i / K;
        const int k = i - r * K;
        float v = 0.f;
        if (base + r < N) {
            v = in[(size_t)(base + r) * K + k];
            if (ACT) v = fmaxf(v + bias[k], 0.f);
        }
        xs[r][k] = v;
    }
    __syncthreads();

    float acc[8];
#pragma unroll
    for (int rr = 0; rr < 8; ++rr) acc[rr] = 0.f;

    for (int k = 0; k < K; ++k) {
        const float wv = Wl[k * 64 + j];
#pragma unroll
        for (int rr = 0; rr < 8; ++rr)
            acc[rr] += xs[rq + rr * 4][k] * wv;
    }

#pragma unroll
    for (int rr = 0; rr < 8; ++rr) {
        const int row = base + rq + rr * 4;
        if (row < N) out[(size_t)row * 64 + j] = acc[rr];
    }
}

// ---------------------------------------------------------------------------
// CSR build: histogram -> exclusive scan -> position scatter
// ---------------------------------------------------------------------------
__global__ __launch_bounds__(256) void hist_kernel(
    const int* __restrict__ rowv, int* __restrict__ deg, int E)
{
    const int e = blockIdx.x * 256 + threadIdx.x;
    if (e < E) atomicAdd(&deg[rowv[e]], 1);
}

// Single-pass hierarchical scan: 1024 threads, each owns a contiguous chunk.
// Pass 1: thread-local sum. Wave shfl scan + 16-entry LDS scan of wave sums.
// Pass 2: re-read chunk (L2-hot), emit exclusive prefix.
__global__ __launch_bounds__(1024) void scan_kernel(
    const int* __restrict__ deg, int* __restrict__ off,
    int* __restrict__ cur, int N, int E)
{
    const int tid = threadIdx.x;
    const int CH  = (N + 1023) >> 10;          // 49 for N=50000
    const int beg = tid * CH;
    const int end = (beg + CH < N) ? beg + CH : N;

    int s = 0;
    for (int i = beg; i < end; ++i) s += deg[i];

    const int lane = tid & 63;
    const int wid  = tid >> 6;                 // 0..15
    int v = s;
#pragma unroll
    for (int d = 1; d < 64; d <<= 1) {
        int t = __shfl_up(v, d);
        if (lane >= d) v += t;
    }
    __shared__ int wsum[16];
    if (lane == 63) wsum[wid] = v;
    __syncthreads();
    if (tid == 0) {
        int acc = 0;
#pragma unroll
        for (int k = 0; k < 16; ++k) { int t = wsum[k]; wsum[k] = acc; acc += t; }
    }
    __syncthreads();

    int run = wsum[wid] + (v - s);             // exclusive prefix for chunk
    for (int i = beg; i < end; ++i) {
        off[i] = run;
        cur[i] = run;
        run += deg[i];
    }
    if (tid == 0) off[N] = E;
}

__global__ __launch_bounds__(256) void build_kernel(
    const int* __restrict__ rowv, const int* __restrict__ colv,
    int* __restrict__ cur, int* __restrict__ scol, int E)
{
    const int e = blockIdx.x * 256 + threadIdx.x;
    if (e >= E) return;
    const int p = atomicAdd(&cur[rowv[e]], 1);
    scol[p] = colv[e];
}

// ---------------------------------------------------------------------------
// Pull aggregation: agg[n][:] = sum_{i in [off[n],off[n+1])} y[scol[i]][:]
// One wave per node; 16 lanes x float4 per edge, 4 edge slots per wave.
// ---------------------------------------------------------------------------
__global__ __launch_bounds__(256) void aggregate(
    const float4* __restrict__ y4, const int* __restrict__ off,
    const int* __restrict__ scol, float4* __restrict__ agg4, int N)
{
    const int n = blockIdx.x * 4 + (threadIdx.x >> 6);
    if (n >= N) return;
    const int lane = threadIdx.x & 63;
    const int f4 = lane & 15;     // which float4 of the 16 (64 feats)
    const int es = lane >> 4;     // edge slot 0..3
    const int beg = off[n], end = off[n + 1];
    float sx = 0.f, sy = 0.f, sz = 0.f, sw = 0.f;
    for (int i = beg + es; i < end; i += 4) {
        const int c = scol[i];
        const float4 v = y4[(size_t)c * 16 + f4];
        sx += v.x; sy += v.y; sz += v.z; sw += v.w;
    }
    sx += __shfl_xor(sx, 16); sy += __shfl_xor(sy, 16);
    sz += __shfl_xor(sz, 16); sw += __shfl_xor(sw, 16);
    sx += __shfl_xor(sx, 32); sy += __shfl_xor(sy, 32);
    sz += __shfl_xor(sz, 32); sw += __shfl_xor(sw, 32);
    if (es == 0) agg4[(size_t)n * 16 + f4] = make_float4(sx, sy, sz, sw);
}

// ---------------------------------------------------------------------------
// Mean-pool (pre-division): hpart[j] += sum_n relu(agg[n][j] + b[j])
// ---------------------------------------------------------------------------
__global__ __launch_bounds__(256) void pool_kernel(
    const float* __restrict__ agg, const float* __restrict__ bias,
    float* __restrict__ hpart, int N)
{
    const int j  = threadIdx.x & 63;
    const int rq = threadIdx.x >> 6;
    const float b = bias[j];
    float s = 0.f;
    for (int n = blockIdx.x * 4 + rq; n < N; n += gridDim.x * 4)
        s += fmaxf(agg[(size_t)n * 64 + j] + b, 0.f);

    __shared__ float red[4][64];
    red[rq][j] = s;
    __syncthreads();
    if (rq == 0) {
        const float t = red[0][j] + red[1][j] + red[2][j] + red[3][j];
        atomicAdd(&hpart[j], t);
    }
}

// ---------------------------------------------------------------------------
// Head MLP: h = hpart/N; t = relu(h@Wf1+bf1); out = sigmoid(t@Wf2+bf2)
// ---------------------------------------------------------------------------
__global__ __launch_bounds__(64) void head_kernel(
    const float* __restrict__ hpart, const float* __restrict__ Wf1,
    const float* __restrict__ bf1, const float* __restrict__ Wf2,
    const float* __restrict__ bf2, float* __restrict__ out, float invN)
{
    __shared__ float hm[64];
    __shared__ float t[32];
    const int tid = threadIdx.x;
    hm[tid] = hpart[tid] * invN;
    __syncthreads();
    if (tid < 32) {
        float a = bf1[tid];
        for (int k = 0; k < 64; ++k) a += hm[k] * Wf1[k * 32 + tid];
        t[tid] = fmaxf(a, 0.f);
    }
    __syncthreads();
    if (tid == 0) {
        float a = bf2[0];
        for (int i = 0; i < 32; ++i) a += t[i] * Wf2[i];
        out[0] = 1.f / (1.f + expf(-a));
    }
}

// ---------------------------------------------------------------------------
extern "C" void kernel_launch(void* const* d_in, const int* in_sizes, int n_in,
                              void* d_out, int out_size, void* d_ws, size_t ws_size,
                              hipStream_t stream)
{
    const float* x   = (const float*)d_in[0];
    const int*   ei  = (const int*)d_in[1];      // [2][E]: row then col
    const float* W1  = (const float*)d_in[2];
    const float* b1  = (const float*)d_in[3];
    const float* W2  = (const float*)d_in[4];
    const float* b2  = (const float*)d_in[5];
    const float* W3  = (const float*)d_in[6];
    const float* b3  = (const float*)d_in[7];
    const float* Wf1 = (const float*)d_in[8];
    const float* bf1 = (const float*)d_in[9];
    const float* Wf2 = (const float*)d_in[10];
    const float* bf2 = (const float*)d_in[11];
    float* out = (float*)d_out;

    const int N = N_NODES;
    const int E = N_EDGES;
    const int* rowv = ei;
    const int* colv = ei + E;

    float* bufA  = (float*)d_ws;                       // [N*64]
    float* bufB  = bufA + (size_t)N * 64;              // [N*64]
    float* hpart = bufB + (size_t)N * 64;              // [64]
    int*   deg   = (int*)(hpart + 64);                 // [N]
    int*   off   = deg + N;                            // [N+1]
    int*   cur   = off + N + 1;                        // [N]
    int*   scol  = cur + N;                            // [E]

    const int gemmGrid = (N + 31) / 32;
    const int edgeGrid = (E + 255) / 256;
    const int aggGrid  = (N + 3) / 4;

    // ---- CSR build (once, reused by all 3 layers) ----
    hipMemsetAsync(deg, 0, (size_t)N * sizeof(int), stream);
    hist_kernel<<<edgeGrid, 256, 0, stream>>>(rowv, deg, E);
    scan_kernel<<<1, 1024, 0, stream>>>(deg, off, cur, N, E);
    build_kernel<<<edgeGrid, 256, 0, stream>>>(rowv, colv, cur, scol, E);

    // ---- layer 1: y = x @ W1 ; agg = A*y ----
    gemm_act<128, false><<<gemmGrid, 256, 0, stream>>>(x, W1, nullptr, bufA, N);
    aggregate<<<aggGrid, 256, 0, stream>>>((const float4*)bufA, off, scol,
                                           (float4*)bufB, N);

    // ---- layer 2 ----
    gemm_act<64, true><<<gemmGrid, 256, 0, stream>>>(bufB, W2, b1, bufA, N);
    aggregate<<<aggGrid, 256, 0, stream>>>((const float4*)bufA, off, scol,
                                           (float4*)bufB, N);

    // ---- layer 3 ----
    gemm_act<64, true><<<gemmGrid, 256, 0, stream>>>(bufB, W3, b2, bufA, N);
    aggregate<<<aggGrid, 256, 0, stream>>>((const float4*)bufA, off, scol,
                                           (float4*)bufB, N);

    // ---- mean pool + head ----
    hipMemsetAsync(hpart, 0, 64 * sizeof(float), stream);
    pool_kernel<<<512, 256, 0, stream>>>(bufB, b3, hpart, N);
    head_kernel<<<1, 64, 0, stream>>>(hpart, Wf1, bf1, Wf2, bf2, out,
                                      1.0f / (float)N);
}

// Round 4
// 386.110 us; speedup vs baseline: 1.2426x; 1.2426x over previous
//
#include <hip/hip_runtime.h>
#include <hip/hip_bf16.h>
#include <math.h>

#define N_NODES 50000
#define N_EDGES 800000

// ---------------------------------------------------------------------------
// GEMM: out[n][j] = sum_k act(in[n][k]) * W[k][j]
//   act(v) = ACT ? max(v + bias[k], 0) : v
// ---------------------------------------------------------------------------
template <int K, bool ACT>
__global__ __launch_bounds__(256) void gemm_act(
    const float* __restrict__ in, const float* __restrict__ W,
    const float* __restrict__ bias, float* __restrict__ out, int N)
{
    __shared__ float Wl[K * 64];
    __shared__ float xs[32][K];

    const int tid = threadIdx.x;
    const int j   = tid & 63;
    const int rq  = tid >> 6;            // 0..3
    const int base = blockIdx.x * 32;

    for (int i = tid; i < K * 64; i += 256) Wl[i] = W[i];

    for (int i = tid; i < 32 * K; i += 256) {
        const int r = i / K;
        const int k = i - r * K;
        float v = 0.f;
        if (base + r < N) {
            v = in[(size_t)(base + r) * K + k];
            if (ACT) v = fmaxf(v + bias[k], 0.f);
        }
        xs[r][k] = v;
    }
    __syncthreads();

    float acc[8];
#pragma unroll
    for (int rr = 0; rr < 8; ++rr) acc[rr] = 0.f;

    for (int k = 0; k < K; ++k) {
        const float wv = Wl[k * 64 + j];
#pragma unroll
        for (int rr = 0; rr < 8; ++rr)
            acc[rr] += xs[rq + rr * 4][k] * wv;
    }

#pragma unroll
    for (int rr = 0; rr < 8; ++rr) {
        const int row = base + rq + rr * 4;
        if (row < N) out[(size_t)row * 64 + j] = acc[rr];
    }
}

// ---------------------------------------------------------------------------
// CSR build: histogram -> two-level exclusive scan -> position scatter
// ---------------------------------------------------------------------------
__global__ __launch_bounds__(256) void hist_kernel(
    const int* __restrict__ rowv, int* __restrict__ deg, int E)
{
    const int e = blockIdx.x * 256 + threadIdx.x;
    if (e < E) atomicAdd(&deg[rowv[e]], 1);
}

// 1) per-block sums of 256-element chunks
__global__ __launch_bounds__(256) void scan_partial(
    const int* __restrict__ deg, int* __restrict__ bsum, int N)
{
    const int tid = threadIdx.x;
    const int i = blockIdx.x * 256 + tid;
    int v = (i < N) ? deg[i] : 0;
#pragma unroll
    for (int d = 1; d < 64; d <<= 1) v += __shfl_xor(v, d);
    __shared__ int w[4];
    const int lane = tid & 63, wid = tid >> 6;
    if (lane == 0) w[wid] = v;
    __syncthreads();
    if (tid == 0) bsum[blockIdx.x] = w[0] + w[1] + w[2] + w[3];
}

// 2) exclusive scan of the (<=256) block sums, one block
__global__ __launch_bounds__(256) void scan_block(
    const int* __restrict__ bsum, int* __restrict__ boff, int nb)
{
    const int tid = threadIdx.x;
    const int lane = tid & 63, wid = tid >> 6;
    const int v = (tid < nb) ? bsum[tid] : 0;
    int incl = v;
#pragma unroll
    for (int d = 1; d < 64; d <<= 1) {
        const int t = __shfl_up(incl, d);
        if (lane >= d) incl += t;
    }
    __shared__ int ws[4];
    if (lane == 63) ws[wid] = incl;
    __syncthreads();
    int add = 0;
#pragma unroll
    for (int k = 0; k < 4; ++k) add += (k < wid) ? ws[k] : 0;
    if (tid < nb) boff[tid] = incl + add - v;   // exclusive
}

// 3) per-chunk inclusive scan + block offset -> off/cur
__global__ __launch_bounds__(256) void scan_emit(
    const int* __restrict__ deg, const int* __restrict__ boff,
    int* __restrict__ off, int* __restrict__ cur, int N, int E)
{
    const int tid = threadIdx.x;
    const int i = blockIdx.x * 256 + tid;
    const int lane = tid & 63, wid = tid >> 6;
    const int v = (i < N) ? deg[i] : 0;
    int incl = v;
#pragma unroll
    for (int d = 1; d < 64; d <<= 1) {
        const int t = __shfl_up(incl, d);
        if (lane >= d) incl += t;
    }
    __shared__ int ws[4];
    if (lane == 63) ws[wid] = incl;
    __syncthreads();
    int add = 0;
#pragma unroll
    for (int k = 0; k < 4; ++k) add += (k < wid) ? ws[k] : 0;
    const int excl = boff[blockIdx.x] + incl + add - v;
    if (i < N) { off[i] = excl; cur[i] = excl; }
    if (i == 0) off[N] = E;
}

__global__ __launch_bounds__(256) void build_kernel(
    const int* __restrict__ rowv, const int* __restrict__ colv,
    int* __restrict__ cur, int* __restrict__ scol, int E)
{
    const int e = blockIdx.x * 256 + threadIdx.x;
    if (e >= E) return;
    const int p = atomicAdd(&cur[rowv[e]], 1);
    scol[p] = colv[e];
}

// ---------------------------------------------------------------------------
// Pull aggregation: agg[n][:] = sum_{i in [off[n],off[n+1])} y[scol[i]][:]
// One wave per node; 16 lanes x float4 per edge, 4 edge slots per wave.
// ---------------------------------------------------------------------------
__global__ __launch_bounds__(256) void aggregate(
    const float4* __restrict__ y4, const int* __restrict__ off,
    const int* __restrict__ scol, float4* __restrict__ agg4, int N)
{
    const int n = blockIdx.x * 4 + (threadIdx.x >> 6);
    if (n >= N) return;
    const int lane = threadIdx.x & 63;
    const int f4 = lane & 15;     // which float4 of the 16 (64 feats)
    const int es = lane >> 4;     // edge slot 0..3
    const int beg = off[n], end = off[n + 1];
    float sx = 0.f, sy = 0.f, sz = 0.f, sw = 0.f;
    for (int i = beg + es; i < end; i += 4) {
        const int c = scol[i];
        const float4 v = y4[(size_t)c * 16 + f4];
        sx += v.x; sy += v.y; sz += v.z; sw += v.w;
    }
    sx += __shfl_xor(sx, 16); sy += __shfl_xor(sy, 16);
    sz += __shfl_xor(sz, 16); sw += __shfl_xor(sw, 16);
    sx += __shfl_xor(sx, 32); sy += __shfl_xor(sy, 32);
    sz += __shfl_xor(sz, 32); sw += __shfl_xor(sw, 32);
    if (es == 0) agg4[(size_t)n * 16 + f4] = make_float4(sx, sy, sz, sw);
}

// ---------------------------------------------------------------------------
// Mean-pool (pre-division): hpart[j] += sum_n relu(agg[n][j] + b[j])
// ---------------------------------------------------------------------------
__global__ __launch_bounds__(256) void pool_kernel(
    const float* __restrict__ agg, const float* __restrict__ bias,
    float* __restrict__ hpart, int N)
{
    const int j  = threadIdx.x & 63;
    const int rq = threadIdx.x >> 6;
    const float b = bias[j];
    float s = 0.f;
    for (int n = blockIdx.x * 4 + rq; n < N; n += gridDim.x * 4)
        s += fmaxf(agg[(size_t)n * 64 + j] + b, 0.f);

    __shared__ float red[4][64];
    red[rq][j] = s;
    __syncthreads();
    if (rq == 0) {
        const float t = red[0][j] + red[1][j] + red[2][j] + red[3][j];
        atomicAdd(&hpart[j], t);
    }
}

// ---------------------------------------------------------------------------
// Head MLP: h = hpart/N; t = relu(h@Wf1+bf1); out = sigmoid(t@Wf2+bf2)
// ---------------------------------------------------------------------------
__global__ __launch_bounds__(64) void head_kernel(
    const float* __restrict__ hpart, const float* __restrict__ Wf1,
    const float* __restrict__ bf1, const float* __restrict__ Wf2,
    const float* __restrict__ bf2, float* __restrict__ out, float invN)
{
    __shared__ float hm[64];
    __shared__ float t[32];
    const int tid = threadIdx.x;
    hm[tid] = hpart[tid] * invN;
    __syncthreads();
    if (tid < 32) {
        float a = bf1[tid];
        for (int k = 0; k < 64; ++k) a += hm[k] * Wf1[k * 32 + tid];
        t[tid] = fmaxf(a, 0.f);
    }
    __syncthreads();
    if (tid == 0) {
        float a = bf2[0];
        for (int i = 0; i < 32; ++i) a += t[i] * Wf2[i];
        out[0] = 1.f / (1.f + expf(-a));
    }
}

// ---------------------------------------------------------------------------
extern "C" void kernel_launch(void* const* d_in, const int* in_sizes, int n_in,
                              void* d_out, int out_size, void* d_ws, size_t ws_size,
                              hipStream_t stream)
{
    const float* x   = (const float*)d_in[0];
    const int*   ei  = (const int*)d_in[1];      // [2][E]: row then col
    const float* W1  = (const float*)d_in[2];
    const float* b1  = (const float*)d_in[3];
    const float* W2  = (const float*)d_in[4];
    const float* b2  = (const float*)d_in[5];
    const float* W3  = (const float*)d_in[6];
    const float* b3  = (const float*)d_in[7];
    const float* Wf1 = (const float*)d_in[8];
    const float* bf1 = (const float*)d_in[9];
    const float* Wf2 = (const float*)d_in[10];
    const float* bf2 = (const float*)d_in[11];
    float* out = (float*)d_out;

    const int N = N_NODES;
    const int E = N_EDGES;
    const int* rowv = ei;
    const int* colv = ei + E;

    float* bufA  = (float*)d_ws;                       // [N*64]
    float* bufB  = bufA + (size_t)N * 64;              // [N*64]
    float* hpart = bufB + (size_t)N * 64;              // [64]
    int*   deg   = (int*)(hpart + 64);                 // [N]
    int*   off   = deg + N;                            // [N+1]
    int*   cur   = off + N + 1;                        // [N]
    int*   scol  = cur + N;                            // [E]
    int*   bsum  = scol + E;                           // [256]
    int*   boff  = bsum + 256;                         // [256]

    const int gemmGrid = (N + 31) / 32;
    const int edgeGrid = (E + 255) / 256;
    const int aggGrid  = (N + 3) / 4;
    const int nb       = (N + 255) / 256;              // 196 scan blocks

    // ---- CSR build (once, reused by all 3 layers) ----
    hipMemsetAsync(deg, 0, (size_t)N * sizeof(int), stream);
    hist_kernel<<<edgeGrid, 256, 0, stream>>>(rowv, deg, E);
    scan_partial<<<nb, 256, 0, stream>>>(deg, bsum, N);
    scan_block<<<1, 256, 0, stream>>>(bsum, boff, nb);
    scan_emit<<<nb, 256, 0, stream>>>(deg, boff, off, cur, N, E);
    build_kernel<<<edgeGrid, 256, 0, stream>>>(rowv, colv, cur, scol, E);

    // ---- layer 1: y = x @ W1 ; agg = A*y ----
    gemm_act<128, false><<<gemmGrid, 256, 0, stream>>>(x, W1, nullptr, bufA, N);
    aggregate<<<aggGrid, 256, 0, stream>>>((const float4*)bufA, off, scol,
                                           (float4*)bufB, N);

    // ---- layer 2 ----
    gemm_act<64, true><<<gemmGrid, 256, 0, stream>>>(bufB, W2, b1, bufA, N);
    aggregate<<<aggGrid, 256, 0, stream>>>((const float4*)bufA, off, scol,
                                           (float4*)bufB, N);

    // ---- layer 3 ----
    gemm_act<64, true><<<gemmGrid, 256, 0, stream>>>(bufB, W3, b2, bufA, N);
    aggregate<<<aggGrid, 256, 0, stream>>>((const float4*)bufA, off, scol,
                                           (float4*)bufB, N);

    // ---- mean pool + head ----
    hipMemsetAsync(hpart, 0, 64 * sizeof(float), stream);
    pool_kernel<<<512, 256, 0, stream>>>(bufB, b3, hpart, N);
    head_kernel<<<1, 64, 0, stream>>>(hpart, Wf1, bf1, Wf2, bf2, out,
                                      1.0f / (float)N);
}